// Round 2
// baseline (748.106 us; speedup 1.0000x reference)
//
#include <hip/hip_runtime.h>
#include <hip/hip_bf16.h>
#include <stdint.h>

typedef __bf16 bf16x8 __attribute__((ext_vector_type(8)));
typedef float f32x4 __attribute__((ext_vector_type(4)));

#define SOFTMAX_SCALE 0.08838834764831845f
#define LOG2E 1.44269504088896f

// load 8 contiguous elements as bf16x8, converting if the source is fp32
__device__ __forceinline__ bf16x8 load8_cvt(const __hip_bfloat16* p) {
  return *(const bf16x8*)p;
}
__device__ __forceinline__ bf16x8 load8_cvt(const float* p) {
  float4 a = *(const float4*)p;
  float4 b = *(const float4*)(p + 4);
  bf16x8 r;
  r[0] = (__bf16)a.x; r[1] = (__bf16)a.y; r[2] = (__bf16)a.z; r[3] = (__bf16)a.w;
  r[4] = (__bf16)b.x; r[5] = (__bf16)b.y; r[6] = (__bf16)b.z; r[7] = (__bf16)b.w;
  return r;
}

// async global->LDS DMA, 16B per lane. LDS dest is wave-uniform base + lane*16;
// swizzled layout achieved by pre-swizzling the per-lane GLOBAL source (rule #21).
__device__ __forceinline__ void gload_lds16(const __hip_bfloat16* g,
                                            __hip_bfloat16* l) {
  __builtin_amdgcn_global_load_lds(
      (__attribute__((address_space(1))) void*)(g),
      (__attribute__((address_space(3))) void*)(l), 16, 0, 0);
}

// ---------------------------------------------------------------------------
// fp32 -> bf16 bulk convert (grid-stride, 16B loads / 16B stores)
// ---------------------------------------------------------------------------
__global__ __launch_bounds__(256) void cvt_f32_bf16(
    const float* __restrict__ in, __hip_bfloat16* __restrict__ out, int n8)
{
  int i = blockIdx.x * blockDim.x + threadIdx.x;
  int stride = gridDim.x * blockDim.x;
  for (; i < n8; i += stride)
    *(bf16x8*)(out + (int64_t)i * 8) = load8_cvt(in + (int64_t)i * 8);
}

// ---------------------------------------------------------------------------
// GEMM core: C = A * B^T, tile 128x128, BK=64, 4 waves. (unchanged, verified)
// ---------------------------------------------------------------------------
template <typename TA, typename TB>
__device__ __forceinline__ void gemm_bt_loop(
    const TA* __restrict__ A,
    const TB* __restrict__ B,
    int K, int m0, int n0,
    __hip_bfloat16* As, __hip_bfloat16* Bs,
    f32x4 acc[4][4])
{
  const int t = threadIdx.x;
  const int w = t >> 6, lane = t & 63;
  const int wm = (w >> 1) * 64, wn = (w & 1) * 64;
  const int l16 = lane & 15, quad = lane >> 4;
  constexpr bool ASYNC = (sizeof(TA) == 2) && (sizeof(TB) == 2);

  for (int k0 = 0; k0 < K; k0 += 64) {
    if constexpr (ASYNC) {
      #pragma unroll
      for (int i = 0; i < 4; ++i) {
        int cb = (w * 4 + i) * 64;            // wave-uniform chunk base
        int idx = cb + lane;
        int row = idx >> 3;
        int chs = (idx & 7) ^ (row & 7);      // pre-swizzled source chunk
        gload_lds16((const __hip_bfloat16*)A + (int64_t)(m0 + row) * K + k0 + chs * 8,
                    As + cb * 8);
        gload_lds16((const __hip_bfloat16*)B + (int64_t)(n0 + row) * K + k0 + chs * 8,
                    Bs + cb * 8);
      }
    } else {
      #pragma unroll
      for (int i = 0; i < 4; ++i) {
        int idx = i * 256 + t;
        int row = idx >> 3, ch = idx & 7;
        int sw = (ch ^ (row & 7)) * 8;
        *(bf16x8*)(As + row * 64 + sw) =
            load8_cvt(A + (int64_t)(m0 + row) * K + k0 + ch * 8);
        *(bf16x8*)(Bs + row * 64 + sw) =
            load8_cvt(B + (int64_t)(n0 + row) * K + k0 + ch * 8);
      }
    }
    __syncthreads();
    #pragma unroll
    for (int ks = 0; ks < 2; ++ks) {
      bf16x8 af[4], bfr[4];
      #pragma unroll
      for (int mt = 0; mt < 4; ++mt) {
        int row = wm + mt * 16 + l16;
        int ch = ks * 4 + quad;
        af[mt] = *(const bf16x8*)(As + row * 64 + ((ch ^ (row & 7)) * 8));
      }
      #pragma unroll
      for (int nt = 0; nt < 4; ++nt) {
        int row = wn + nt * 16 + l16;
        int ch = ks * 4 + quad;
        bfr[nt] = *(const bf16x8*)(Bs + row * 64 + ((ch ^ (row & 7)) * 8));
      }
      #pragma unroll
      for (int mt = 0; mt < 4; ++mt)
        #pragma unroll
        for (int nt = 0; nt < 4; ++nt)
          acc[mt][nt] = __builtin_amdgcn_mfma_f32_16x16x32_bf16(
              af[mt], bfr[nt], acc[mt][nt], 0, 0, 0);
    }
    __syncthreads();
  }
}

// ---------------------------------------------------------------------------
// Kernel 1: QKV projection (unchanged, verified)
// ---------------------------------------------------------------------------
template <typename TA, typename TB>
__global__ __launch_bounds__(256) void qkv_gemm(
    const TA* __restrict__ A,
    const TB* __restrict__ W,
    __hip_bfloat16* __restrict__ qb,
    __hip_bfloat16* __restrict__ kb,
    __hip_bfloat16* __restrict__ vb)
{
  __shared__ __align__(16) __hip_bfloat16 As[128 * 64];
  __shared__ __align__(16) __hip_bfloat16 Bs[128 * 64];
  const f32x4 z4 = {0.f, 0.f, 0.f, 0.f};
  f32x4 acc[4][4];
  #pragma unroll
  for (int mt = 0; mt < 4; ++mt)
    #pragma unroll
    for (int nt = 0; nt < 4; ++nt) acc[mt][nt] = z4;

  const int K = 2048;
  const int n0 = blockIdx.x * 128, m0 = blockIdx.y * 128;
  gemm_bt_loop(A, W, K, m0, n0, As, Bs, acc);

  const int t = threadIdx.x;
  const int w = t >> 6, lane = t & 63;
  const int wm = (w >> 1) * 64, wn = (w & 1) * 64;
  const int l16 = lane & 15, quad = lane >> 4;
  __hip_bfloat16* bufs[3] = {qb, kb, vb};
  #pragma unroll
  for (int nt = 0; nt < 4; ++nt) {
    int gn = n0 + wn + nt * 16 + l16;
    int which = gn >> 11;          // 0=q 1=k 2=v
    int hc = gn & 2047;
    int head = hc >> 7, d = hc & 127;
    __hip_bfloat16* dst = bufs[which];
    #pragma unroll
    for (int mt = 0; mt < 4; ++mt) {
      #pragma unroll
      for (int r = 0; r < 4; ++r) {
        int gm = m0 + wm + mt * 16 + quad * 4 + r;
        int bb = gm >> 11, s = gm & 2047;
        float val = acc[mt][nt][r];
        val = fminf(8.f, fmaxf(-8.f, val));
        dst[(((int64_t)(bb * 16 + head) * 2048 + s) << 7) + d] =
            __float2bfloat16(val);
      }
    }
  }
}

// ---------------------------------------------------------------------------
// Kernel 2: V transpose per head (unchanged)
// ---------------------------------------------------------------------------
__global__ __launch_bounds__(256) void transpose_v(
    const __hip_bfloat16* __restrict__ V,
    __hip_bfloat16* __restrict__ Vt)
{
  __shared__ __hip_bfloat16 tile[64][68];
  const int bh = blockIdx.z;
  const int s0 = blockIdx.x * 64;
  const int d0 = blockIdx.y * 64;
  const int t = threadIdx.x;
  const int c = t & 63, rq = t >> 6;
  const __hip_bfloat16* Vp = V + (int64_t)bh * 2048 * 128;
  #pragma unroll
  for (int j = 0; j < 16; ++j) {
    int r = rq * 16 + j;
    tile[r][c] = Vp[(int64_t)(s0 + r) * 128 + d0 + c];
  }
  __syncthreads();
  __hip_bfloat16* Vo = Vt + (int64_t)bh * 128 * 2048;
  #pragma unroll
  for (int j = 0; j < 16; ++j) {
    int dd = rq * 16 + j;
    Vo[(int64_t)(d0 + dd) * 2048 + s0 + c] = tile[c][dd];
  }
}

// ---------------------------------------------------------------------------
// Kernel 3: flash attention, pipelined.
// KVBLK=64, double-buffered K/V via global_load_lds; bias prefetched one tile
// ahead straight into registers (never LDS); counted s_waitcnt vmcnt(24) + raw
// s_barrier so next-tile loads stay in flight across the barrier (T3/T4).
// P is per-wave-private LDS -> no barriers around it. 2 barriers/tile total.
// LDS = 72 KB -> 2 blocks/CU. blockIdx.y -> (h,b) so the two batches sharing a
// bias tile are dispatch-adjacent (bias HBM traffic halves via L2).
// ---------------------------------------------------------------------------
__device__ __forceinline__ void attn_step(
    int kt, int ktmax, int q0,
    const __hip_bfloat16* Kbase, const __hip_bfloat16* Vbase, const float* Bb,
    __hip_bfloat16* Kcur, __hip_bfloat16* Vcur,
    __hip_bfloat16* Knxt, __hip_bfloat16* Vnxt,
    __hip_bfloat16* Ps,
    const bf16x8 (&qf)[4],
    float (&bcur)[16], float (&bnxt)[16],
    f32x4 (&O)[8], float (&m_r)[4], float (&l_r)[4],
    int w, int lane, int l16, int quad)
{
  // ---- issue next tile (K/V DMA + bias reg loads), then counted wait ----
  if (kt < ktmax) {
    const __hip_bfloat16* Kp = Kbase + (int64_t)(kt + 1) * 64 * 128;
    const __hip_bfloat16* Vp = Vbase + (kt + 1) * 64;
    #pragma unroll
    for (int i = 0; i < 4; ++i) {
      int cb = (w * 4 + i) * 64;
      int idx = cb + lane;
      { int row = idx >> 4, chs = (idx & 15) ^ (row & 15);
        gload_lds16(Kp + row * 128 + chs * 8, Knxt + cb * 8); }
      { int row = idx >> 3, chs = (idx & 7) ^ (row & 7);
        gload_lds16(Vp + (int64_t)row * 2048 + chs * 8, Vnxt + cb * 8); }
    }
    const float* bp = Bb + (int64_t)(q0 + w * 16 + quad * 4) * 2048
                      + (kt + 1) * 64 + l16;
    #pragma unroll
    for (int nt = 0; nt < 4; ++nt)
      #pragma unroll
      for (int r = 0; r < 4; ++r)
        bnxt[nt * 4 + r] = bp[(int64_t)r * 2048 + nt * 16];
    // 8 DMA + 16 bias for tile kt+1 stay in flight; everything older drains.
    asm volatile("s_waitcnt vmcnt(24)" ::: "memory");
  } else {
    asm volatile("s_waitcnt vmcnt(0)" ::: "memory");
  }
  __builtin_amdgcn_s_barrier();      // tile kt LDS ready on all waves

  // ---- S = Q * K^T (16 q-rows x 64 keys per wave) ----
  const f32x4 z4 = {0.f, 0.f, 0.f, 0.f};
  f32x4 S[4];
  #pragma unroll
  for (int nt = 0; nt < 4; ++nt) S[nt] = z4;
  __builtin_amdgcn_s_setprio(1);
  #pragma unroll
  for (int ks = 0; ks < 4; ++ks) {
    int ch = ks * 4 + quad;
    bf16x8 kf[4];
    #pragma unroll
    for (int nt = 0; nt < 4; ++nt) {
      int row = nt * 16 + l16;
      kf[nt] = *(const bf16x8*)(Kcur + row * 128 + ((ch ^ (row & 15)) * 8));
    }
    #pragma unroll
    for (int nt = 0; nt < 4; ++nt)
      S[nt] = __builtin_amdgcn_mfma_f32_16x16x32_bf16(
          qf[ks], kf[nt], S[nt], 0, 0, 0);
  }
  __builtin_amdgcn_s_setprio(0);

  // ---- scale + bias(regs) + causal mask ----
  const bool diag = (kt == ktmax);
  #pragma unroll
  for (int r = 0; r < 4; ++r) {
    int trow = w * 16 + quad * 4 + r;
    int gq = q0 + trow;
    #pragma unroll
    for (int nt = 0; nt < 4; ++nt) {
      int col = kt * 64 + nt * 16 + l16;
      float sv = S[nt][r] * SOFTMAX_SCALE + bcur[nt * 4 + r];
      if (diag && col > gq) sv = -3.0e38f;
      S[nt][r] = sv;
    }
  }

  // ---- online softmax (row stats across the 16 l16 lanes) ----
  #pragma unroll
  for (int r = 0; r < 4; ++r) {
    float rm = fmaxf(fmaxf(S[0][r], S[1][r]), fmaxf(S[2][r], S[3][r]));
    rm = fmaxf(rm, __shfl_xor(rm, 1, 64));
    rm = fmaxf(rm, __shfl_xor(rm, 2, 64));
    rm = fmaxf(rm, __shfl_xor(rm, 4, 64));
    rm = fmaxf(rm, __shfl_xor(rm, 8, 64));
    float mo = m_r[r];
    float mn = fmaxf(mo, rm);
    float alpha = exp2f((mo - mn) * LOG2E);
    float rs = 0.f;
    #pragma unroll
    for (int nt = 0; nt < 4; ++nt) {
      float pv = exp2f((S[nt][r] - mn) * LOG2E);
      S[nt][r] = pv;
      rs += pv;
    }
    rs += __shfl_xor(rs, 1, 64);
    rs += __shfl_xor(rs, 2, 64);
    rs += __shfl_xor(rs, 4, 64);
    rs += __shfl_xor(rs, 8, 64);
    m_r[r] = mn;
    l_r[r] = l_r[r] * alpha + rs;
    #pragma unroll
    for (int nt2 = 0; nt2 < 8; ++nt2) O[nt2][r] *= alpha;
  }

  // ---- P -> per-wave-private LDS (no barrier: only own wave reads it) ----
  #pragma unroll
  for (int r = 0; r < 4; ++r) {
    int trow = w * 16 + quad * 4 + r;
    #pragma unroll
    for (int nt = 0; nt < 4; ++nt) {
      int col = nt * 16 + l16;
      Ps[trow * 64 + (((col >> 3) ^ (trow & 7)) << 3) + (col & 7)] =
          __float2bfloat16(S[nt][r]);
    }
  }

  // ---- O += P * V ----
  __builtin_amdgcn_s_setprio(1);
  #pragma unroll
  for (int ksp = 0; ksp < 2; ++ksp) {
    int ch = ksp * 4 + quad;
    int prow = w * 16 + l16;
    bf16x8 pf = *(const bf16x8*)(Ps + prow * 64 + ((ch ^ (prow & 7)) * 8));
    #pragma unroll
    for (int nt = 0; nt < 8; ++nt) {
      int row = nt * 16 + l16;
      bf16x8 vf = *(const bf16x8*)(Vcur + row * 64 + ((ch ^ (row & 7)) * 8));
      O[nt] = __builtin_amdgcn_mfma_f32_16x16x32_bf16(pf, vf, O[nt], 0, 0, 0);
    }
  }
  __builtin_amdgcn_s_setprio(0);

  // all LDS reads of tile kt retired before any wave's next DMA overwrites
  asm volatile("s_waitcnt lgkmcnt(0)" ::: "memory");
  __builtin_amdgcn_s_barrier();
}

__global__ __launch_bounds__(256, 2) void attn_kernel(
    const __hip_bfloat16* __restrict__ Q,
    const __hip_bfloat16* __restrict__ Kg,
    const __hip_bfloat16* __restrict__ Vt,
    const float* __restrict__ bias,
    __hip_bfloat16* __restrict__ ctx)
{
  __shared__ __align__(16) __hip_bfloat16 KsBuf[2][64 * 128];  // 2 x 16 KB
  __shared__ __align__(16) __hip_bfloat16 VsBuf[2][128 * 64];  // 2 x 16 KB
  __shared__ __align__(16) __hip_bfloat16 Ps[64 * 64];         // 8 KB

  const int t = threadIdx.x;
  const int w = t >> 6, lane = t & 63;
  const int l16 = lane & 15, quad = lane >> 4;

  const int y = blockIdx.y;
  const int h = y >> 1, b = y & 1;     // b=0/b=1 with same h are adjacent
  const int bh = b * 16 + h;
  const int qt = 31 - (int)blockIdx.x; // heavy q-tiles first
  const int q0 = qt * 64;
  const int ktmax = qt;                // 64-wide key tiles: 0..qt

  // Q fragments: wave w covers q rows [q0 + w*16, +16)
  bf16x8 qf[4];
  {
    const __hip_bfloat16* Qp = Q + ((int64_t)bh * 2048 + q0 + w * 16) * 128;
    #pragma unroll
    for (int ks = 0; ks < 4; ++ks)
      qf[ks] = *(const bf16x8*)(Qp + l16 * 128 + ks * 32 + quad * 8);
  }

  const f32x4 z4 = {0.f, 0.f, 0.f, 0.f};
  f32x4 O[8];
  #pragma unroll
  for (int nt = 0; nt < 8; ++nt) O[nt] = z4;
  float m_r[4], l_r[4];
  #pragma unroll
  for (int r = 0; r < 4; ++r) { m_r[r] = -3.0e38f; l_r[r] = 0.f; }

  const __hip_bfloat16* Kbase = Kg + (int64_t)bh * 2048 * 128;
  const __hip_bfloat16* Vbase = Vt + (int64_t)bh * 128 * 2048;
  const float* Bb = bias + (int64_t)h * 2048 * 2048;

  float bA[16], bB[16];

  // prologue: stage tile 0 (DMA) + bias 0 (regs)
  {
    #pragma unroll
    for (int i = 0; i < 4; ++i) {
      int cb = (w * 4 + i) * 64;
      int idx = cb + lane;
      { int row = idx >> 4, chs = (idx & 15) ^ (row & 15);
        gload_lds16(Kbase + row * 128 + chs * 8, KsBuf[0] + cb * 8); }
      { int row = idx >> 3, chs = (idx & 7) ^ (row & 7);
        gload_lds16(Vbase + (int64_t)row * 2048 + chs * 8, VsBuf[0] + cb * 8); }
    }
    const float* bp = Bb + (int64_t)(q0 + w * 16 + quad * 4) * 2048 + l16;
    #pragma unroll
    for (int nt = 0; nt < 4; ++nt)
      #pragma unroll
      for (int r = 0; r < 4; ++r)
        bA[nt * 4 + r] = bp[(int64_t)r * 2048 + nt * 16];
  }

  for (int kt = 0; kt <= ktmax; kt += 2) {
    attn_step(kt, ktmax, q0, Kbase, Vbase, Bb,
              KsBuf[0], VsBuf[0], KsBuf[1], VsBuf[1], Ps, qf,
              bA, bB, O, m_r, l_r, w, lane, l16, quad);
    if (kt + 1 <= ktmax)
      attn_step(kt + 1, ktmax, q0, Kbase, Vbase, Bb,
                KsBuf[1], VsBuf[1], KsBuf[0], VsBuf[0], Ps, qf,
                bB, bA, O, m_r, l_r, w, lane, l16, quad);
  }

  // epilogue: ctx[b*2048 + q][h*128 + d] = O / l   (bf16)
  #pragma unroll
  for (int r = 0; r < 4; ++r) {
    int trow = w * 16 + quad * 4 + r;
    int gm = b * 2048 + q0 + trow;
    float inv = 1.f / l_r[r];
    __hip_bfloat16* crow = ctx + (int64_t)gm * 2048 + h * 128;
    #pragma unroll
    for (int nt = 0; nt < 8; ++nt)
      crow[nt * 16 + l16] = __float2bfloat16(O[nt][r] * inv);
  }
}

// ---------------------------------------------------------------------------
// Kernel 4: output projection (unchanged)
// ---------------------------------------------------------------------------
template <typename TB>
__global__ __launch_bounds__(256) void out_gemm(
    const __hip_bfloat16* __restrict__ A,
    const TB* __restrict__ W,
    float* __restrict__ out)
{
  __shared__ __align__(16) __hip_bfloat16 As[128 * 64];
  __shared__ __align__(16) __hip_bfloat16 Bs[128 * 64];
  const f32x4 z4 = {0.f, 0.f, 0.f, 0.f};
  f32x4 acc[4][4];
  #pragma unroll
  for (int mt = 0; mt < 4; ++mt)
    #pragma unroll
    for (int nt = 0; nt < 4; ++nt) acc[mt][nt] = z4;

  const int K = 2048;
  const int n0 = blockIdx.x * 128, m0 = blockIdx.y * 128;
  gemm_bt_loop(A, W, K, m0, n0, As, Bs, acc);

  const int t = threadIdx.x;
  const int w = t >> 6, lane = t & 63;
  const int wm = (w >> 1) * 64, wn = (w & 1) * 64;
  const int l16 = lane & 15, quad = lane >> 4;
  #pragma unroll
  for (int mt = 0; mt < 4; ++mt) {
    #pragma unroll
    for (int r = 0; r < 4; ++r) {
      int gm = m0 + wm + mt * 16 + quad * 4 + r;
      #pragma unroll
      for (int nt = 0; nt < 4; ++nt) {
        int gn = n0 + wn + nt * 16 + l16;
        out[(int64_t)gm * 2048 + gn] = acc[mt][nt][r];
      }
    }
  }
}

// ---------------------------------------------------------------------------
extern "C" void kernel_launch(void* const* d_in, const int* in_sizes, int n_in,
                              void* d_out, int out_size, void* d_ws, size_t ws_size,
                              hipStream_t stream) {
  const float* hs   = (const float*)d_in[0];
  const float* bias = (const float*)d_in[1];
  // d_in[2] = attention_mask: pure causal, applied analytically; never read.
  const float* Wqkv = (const float*)d_in[3];
  const float* Wout = (const float*)d_in[4];
  float* out = (float*)d_out;

  __hip_bfloat16* ws = (__hip_bfloat16*)d_ws;
  const size_t SEG = (size_t)32 * 2048 * 128;   // 8,388,608 elements (16 MB)
  __hip_bfloat16* q   = ws;
  __hip_bfloat16* k   = ws + SEG;
  __hip_bfloat16* v   = ws + 2 * SEG;
  __hip_bfloat16* vt  = ws + 3 * SEG;
  __hip_bfloat16* ctx = ws + 2 * SEG;           // aliases v (dead after transpose)

  const size_t NW_QKV = (size_t)6144 * 2048;    // 12,582,912
  const size_t NW_OUT = (size_t)2048 * 2048;    //  4,194,304
  const size_t need_bytes = (4 * SEG + NW_QKV + SEG) * sizeof(__hip_bfloat16);

  if (ws_size >= need_bytes) {
    // fast path: pre-convert operands to bf16, halving GEMM staging bytes
    __hip_bfloat16* wqkvb = ws + 4 * SEG;
    __hip_bfloat16* hsb   = wqkvb + NW_QKV;
    __hip_bfloat16* woutb = wqkvb;              // aliases wqkvb (dead after qkv)
    cvt_f32_bf16<<<1024, 256, 0, stream>>>(hs, hsb, (int)(SEG / 8));
    cvt_f32_bf16<<<1024, 256, 0, stream>>>(Wqkv, wqkvb, (int)(NW_QKV / 8));
    qkv_gemm<__hip_bfloat16, __hip_bfloat16>
        <<<dim3(48, 32), 256, 0, stream>>>(hsb, wqkvb, q, k, v);
    transpose_v<<<dim3(32, 2, 32), 256, 0, stream>>>(v, vt);
    cvt_f32_bf16<<<1024, 256, 0, stream>>>(Wout, woutb, (int)(NW_OUT / 8));
    attn_kernel<<<dim3(32, 32), 256, 0, stream>>>(q, k, vt, bias, ctx);
    out_gemm<__hip_bfloat16><<<dim3(16, 32), 256, 0, stream>>>(ctx, woutb, out);
  } else {
    // fallback: fp32-direct staging (round-2 proven path)
    qkv_gemm<float, float><<<dim3(48, 32), 256, 0, stream>>>(hs, Wqkv, q, k, v);
    transpose_v<<<dim3(32, 2, 32), 256, 0, stream>>>(v, vt);
    attn_kernel<<<dim3(32, 32), 256, 0, stream>>>(q, k, vt, bias, ctx);
    out_gemm<float><<<dim3(16, 32), 256, 0, stream>>>(ctx, Wout, out);
  }
}